// Round 8
// baseline (470.741 us; speedup 1.0000x reference)
//
#include <hip/hip_runtime.h>
#include <cstdint>

typedef _Float16 f16x8 __attribute__((ext_vector_type(8)));
typedef float f32x4 __attribute__((ext_vector_type(4)));

typedef __attribute__((address_space(1))) void gvoid;
typedef __attribute__((address_space(3))) void lvoid;

__device__ __forceinline__ void gload16(const void* g, void* l) {
    __builtin_amdgcn_global_load_lds((gvoid*)g, (lvoid*)l, 16, 0, 0);
}

__device__ __forceinline__ void bar() {
    asm volatile("" ::: "memory");
    __builtin_amdgcn_s_barrier();
    asm volatile("" ::: "memory");
}
#define WAITV(N) asm volatile("s_waitcnt vmcnt(" #N ")" ::: "memory")
// Counted lgkm wait + schedule pin (rule #18).
#define WAITL(N) do { asm volatile("s_waitcnt lgkmcnt(" #N ")" ::: "memory"); \
                      __builtin_amdgcn_sched_barrier(0); } while (0)

// ---------------------------------------------------------------------------
__global__ __launch_bounds__(256) void downsample_kernel(const float* __restrict__ f,
                                                         const float* __restrict__ b,
                                                         float* __restrict__ fds,
                                                         float* __restrict__ bds) {
    int idx = blockIdx.x * 256 + threadIdx.x;
    const float* src = blockIdx.y ? b : f;
    float* dst = blockIdx.y ? bds : fds;
    int bb = idx >> 19;
    int r = idx & 524287;
    int c = r >> 12, a = (r >> 6) & 63, v = r & 63;
    dst[idx] = src[(size_t)bb * 2097152 + (size_t)c * 16384 + (2 * a) * 128 + 2 * v];
}

// ---------------------------------------------------------------------------
__global__ __launch_bounds__(256) void build_mm_kernel(const float* __restrict__ mask,
                                                       float* __restrict__ mm) {
    int l = blockIdx.x * 256 + threadIdx.x;
    if (l >= 4096) return;
    int i = l >> 6, j = l & 63;
    float s = 0.f;
    #pragma unroll
    for (int dy = 0; dy < 3; ++dy)
        #pragma unroll
        for (int dx = 0; dx < 3; ++dx) {
            int a = i + dy - 1, b = j + dx - 1;
            if ((unsigned)a < 64u && (unsigned)b < 64u)
                s += mask[(2 * a) * 128 + 2 * b];
        }
    mm[l] = (s == 0.0f) ? 1.0f : 0.0f;
}

// ---------------------------------------------------------------------------
__global__ __launch_bounds__(256) void build_fpatch_kernel(const float* __restrict__ fds,
                                                           _Float16* __restrict__ Fp) {
    int bb = blockIdx.x >> 12;
    int p = blockIdx.x & 4095;
    const float* fb = fds + (size_t)bb * 524288;
    _Float16* Fpb = Fp + (size_t)bb * 4718592;
    int u = p >> 6, v = p & 63;
    for (int k = threadIdx.x; k < 1152; k += 256) {
        int c = k / 9;
        int s = k - 9 * c;
        int dy = s / 3, dx = s - 3 * dy;
        int a = u + dy - 1, bcol = v + dx - 1;
        float val = 0.f;
        if ((unsigned)a < 64u && (unsigned)bcol < 64u)
            val = fb[c * 4096 + a * 64 + bcol];
        Fpb[(size_t)p * 1152 + k] = (_Float16)val;
    }
}

// ---------------------------------------------------------------------------
__global__ __launch_bounds__(256) void build_wn_kernel(const float* __restrict__ bds,
                                                       _Float16* __restrict__ Wn) {
    __shared__ float wsh[1152];
    __shared__ float red[4];
    int bb = blockIdx.x >> 12;
    int l = blockIdx.x & 4095;
    const float* bp = bds + (size_t)bb * 524288;
    _Float16* Wnb = Wn + (size_t)bb * 4718592;
    int i = l >> 6, j = l & 63;
    float sq = 0.f;
    for (int k = threadIdx.x; k < 1152; k += 256) {
        int c = k / 9;
        int s = k - 9 * c;
        int dy = s / 3, dx = s - 3 * dy;
        int a = i + dy - 1, bcol = j + dx - 1;
        float val = 0.f;
        if ((unsigned)a < 64u && (unsigned)bcol < 64u)
            val = bp[c * 4096 + a * 64 + bcol];
        wsh[k] = val;
        sq += val * val;
    }
    #pragma unroll
    for (int off = 32; off > 0; off >>= 1) sq += __shfl_xor(sq, off);
    if ((threadIdx.x & 63) == 0) red[threadIdx.x >> 6] = sq;
    __syncthreads();
    float total = red[0] + red[1] + red[2] + red[3] + 0.1152f;
    float rinv = 1.0f / sqrtf(total);
    for (int k = threadIdx.x; k < 1152; k += 256)
        Wnb[(size_t)l * 1152 + k] = (_Float16)(wsh[k] * rinv);
}

// ---------------------------------------------------------------------------
__global__ __launch_bounds__(256) void build_vt_kernel(const float* __restrict__ b,
                                                       _Float16* __restrict__ Vt) {
    int bb = blockIdx.x >> 11;
    int n = blockIdx.x & 2047;
    const float* bp = b + (size_t)bb * 2097152;
    _Float16* Vtb = Vt + (size_t)bb * 8388608;
    int c = n >> 4, r = n & 15, rh = r >> 2, rw = r & 3;
    const float* bc = bp + (size_t)c * 16384;
    for (int l = threadIdx.x; l < 4096; l += 256) {
        int lh = l >> 6, lw = l & 63;
        int row = 2 * lh + rh - 1, col = 2 * lw + rw - 1;
        float val = 0.f;
        if ((unsigned)row < 128u && (unsigned)col < 128u)
            val = bc[row * 128 + col];
        Vtb[(size_t)n * 4096 + l] = (_Float16)val;
    }
}

// ---------------------------------------------------------------------------
// 256x256/BK=64 core, BIG WAVE TILES: 4 waves (1/SIMD), each owns 128x128.
// LDS read volume per FLOP drops 1.5x vs the 8-wave 128x64 config (0.0234 ->
// 0.0156 B/FLOP) -- the pipe that R2-R6 proved saturated. acc = 256 VGPR
// (launch_bounds(256,1): full 512 budget). No TLP at 1 wave/SIMD, so the R6
// rotated-read + counted-lgkm schedule is load-bearing: reads(p+1) issue
// under MM(p)'s queued MFMAs; MFMAs drain across barriers (acc reuse is 8
// phases away). Region/vmcnt calculus = R1/R6 with 4-load regions:
// WAITV(8) leaves the 2 most recent regions; lgkm counts 4 (LDA) / 12
// (LDA+LDB). Per-element accumulation order unchanged -> numerics identical.
template <int KSTR, int NTILES>
__device__ __forceinline__ void gemm_core(const _Float16* __restrict__ A,
                                          const _Float16* __restrict__ Bt,
                                          _Float16* __restrict__ C,
                                          _Float16* __restrict__ AsB,
                                          _Float16* __restrict__ BsB) {
    const int tid = threadIdx.x;
    const int lane = tid & 63;
    const int wave = tid >> 6;        // 0..3
    const int quad = lane >> 4;
    const int l16 = lane & 15;
    const int wm = wave >> 1;         // 128-row half of M-tile
    const int wn2 = wave & 1;         // 128-col half of N-tile
    const int bm = blockIdx.y * 256;
    const int bn = blockIdx.x * 256;

    f32x4 acc[8][8] = {};
    f16x8 afrA[4], afrB[4], bfrA[8], bfrB[8];

    // staging source offsets (pre-swizzled global addresses; 4 slots/thread)
    int offA[4], offB[4];
    #pragma unroll
    for (int rd = 0; rd < 4; ++rd) {
        int s = rd * 256 + tid;
        int sr = s >> 2;
        int r = sr ^ ((sr >> 2) & 1);
        int q = (s & 3) ^ (r & 3);
        offA[rd] = (bm + r) * KSTR + q * 8;
        offB[rd] = (bn + r) * KSTR + q * 8;
    }

#define STAGE_A(buf, kt, kh) do {                                                          \
        _Pragma("unroll")                                                                  \
        for (int rd = 0; rd < 4; ++rd)                                                     \
            gload16(A + offA[rd] + (kt) * 64 + (kh) * 32,                                  \
                    AsB + ((buf) * 2 + (kh)) * 8192 + (rd * 256 + tid) * 8);               \
    } while (0)
#define STAGE_B(buf, kt, kh) do {                                                          \
        _Pragma("unroll")                                                                  \
        for (int rd = 0; rd < 4; ++rd)                                                     \
            gload16(Bt + offB[rd] + (kt) * 64 + (kh) * 32,                                 \
                    BsB + ((buf) * 2 + (kh)) * 8192 + (rd * 256 + tid) * 8);               \
    } while (0)

    const int c2 = (l16 >> 2) & 1;
    const int rdoff = ((l16 ^ c2) * 32) + ((quad ^ (l16 & 3)) * 8);

#define LDA(dst, buf, kh, mh) do {                                                         \
        _Pragma("unroll")                                                                  \
        for (int mi = 0; mi < 4; ++mi)                                                     \
            dst[mi] = *(const f16x8*)&AsB[((buf) * 2 + (kh)) * 8192 +                      \
                (wm * 128 + ((mh) * 4 + mi) * 16) * 32 + rdoff];                           \
    } while (0)
#define LDB(dst, buf, kh) do {                                                             \
        _Pragma("unroll")                                                                  \
        for (int ni = 0; ni < 8; ++ni)                                                     \
            dst[ni] = *(const f16x8*)&BsB[((buf) * 2 + (kh)) * 8192 +                      \
                (wn2 * 128 + ni * 16) * 32 + rdoff];                                       \
    } while (0)
#define MM(af, bf, mh) do {                                                                \
        __builtin_amdgcn_s_setprio(1);                                                     \
        _Pragma("unroll")                                                                  \
        for (int mi = 0; mi < 4; ++mi)                                                     \
            _Pragma("unroll")                                                              \
            for (int ni = 0; ni < 8; ++ni)                                                 \
                acc[(mh) * 4 + mi][ni] = __builtin_amdgcn_mfma_f32_16x16x32_f16(           \
                    af[mi], bf[ni], acc[(mh) * 4 + mi][ni], 0, 0, 0);                      \
        __builtin_amdgcn_s_setprio(0);                                                     \
    } while (0)

    // prologue: stage buf0 (tile0, both kh) + buf1.kh0 (tile1); preload p1.
    STAGE_A(0, 0, 0); STAGE_B(0, 0, 0);
    STAGE_A(0, 0, 1); STAGE_B(0, 0, 1);
    STAGE_A(1, 1, 0); STAGE_B(1, 1, 0);
    WAITV(8);
    bar();
    LDA(afrA, 0, 0, 0); LDB(bfrA, 0, 0);

    #pragma unroll 1
    for (int i = 0; i < NTILES / 2 - 1; ++i) {
        const int t0 = 2 * i;
        // p1
        STAGE_A(1, t0 + 1, 1);
        bar();
        LDA(afrB, 0, 0, 1);
        WAITL(4);
        MM(afrA, bfrA, 0);
        bar();
        // p2
        STAGE_B(1, t0 + 1, 1);
        bar();
        LDA(afrA, 0, 1, 0); LDB(bfrB, 0, 1);
        WAITL(12);
        MM(afrB, bfrA, 1);
        bar();
        // p3
        STAGE_A(0, t0 + 2, 0);
        bar();
        LDA(afrB, 0, 1, 1);
        WAITL(4);
        MM(afrA, bfrB, 0);
        bar();
        // p4
        STAGE_B(0, t0 + 2, 0); WAITV(8);
        bar();
        LDA(afrA, 1, 0, 0); LDB(bfrA, 1, 0);
        WAITL(12);
        MM(afrB, bfrB, 1);
        bar();
        // p5
        STAGE_A(0, t0 + 2, 1);
        bar();
        LDA(afrB, 1, 0, 1);
        WAITL(4);
        MM(afrA, bfrA, 0);
        bar();
        // p6
        STAGE_B(0, t0 + 2, 1);
        bar();
        LDA(afrA, 1, 1, 0); LDB(bfrB, 1, 1);
        WAITL(12);
        MM(afrB, bfrA, 1);
        bar();
        // p7
        STAGE_A(1, t0 + 3, 0);
        bar();
        LDA(afrB, 1, 1, 1);
        WAITL(4);
        MM(afrA, bfrB, 0);
        bar();
        // p8
        STAGE_B(1, t0 + 3, 0); WAITV(8);
        bar();
        LDA(afrA, 0, 0, 0); LDB(bfrA, 0, 0);
        WAITL(12);
        MM(afrB, bfrB, 1);
        bar();
    }

    // epilogue: tiles NTILES-2 (buf0), NTILES-1 (buf1); stage buf1.kh1 only.
    STAGE_A(1, NTILES - 1, 1);
    bar();
    LDA(afrB, 0, 0, 1);
    WAITL(4);
    MM(afrA, bfrA, 0);
    bar();
    STAGE_B(1, NTILES - 1, 1);
    bar();
    LDA(afrA, 0, 1, 0); LDB(bfrB, 0, 1);
    WAITL(12);
    MM(afrB, bfrA, 1);
    bar();
    bar();
    LDA(afrB, 0, 1, 1);
    WAITL(4);
    MM(afrA, bfrB, 0);
    bar();
    WAITV(8);
    bar();
    LDA(afrA, 1, 0, 0); LDB(bfrA, 1, 0);
    WAITL(12);
    MM(afrB, bfrB, 1);
    bar();
    bar();
    LDA(afrB, 1, 0, 1);
    WAITL(4);
    MM(afrA, bfrA, 0);
    bar();
    WAITV(0);
    bar();
    LDA(afrA, 1, 1, 0); LDB(bfrB, 1, 1);
    WAITL(12);
    MM(afrB, bfrA, 1);
    bar();
    bar();
    LDA(afrB, 1, 1, 1);
    WAITL(4);
    MM(afrA, bfrB, 0);
    bar();
    WAITL(0);
    MM(afrB, bfrB, 1);

#undef STAGE_A
#undef STAGE_B
#undef LDA
#undef LDB
#undef MM

    #pragma unroll
    for (int mi = 0; mi < 8; ++mi)
        #pragma unroll
        for (int ni = 0; ni < 8; ++ni)
            #pragma unroll
            for (int r = 0; r < 4; ++r) {
                int row = bm + wm * 128 + mi * 16 + quad * 4 + r;
                int col = bn + wn2 * 128 + ni * 16 + l16;
                C[(size_t)row * 4096 + col] = (_Float16)acc[mi][ni][r];
            }
}

// ---------------------------------------------------------------------------
__global__ __launch_bounds__(256, 1) void gemm1_kernel(const _Float16* __restrict__ Fp,
                                                       const _Float16* __restrict__ Wn,
                                                       _Float16* __restrict__ S0) {
    __shared__ __align__(16) _Float16 As[2][2][8192];
    __shared__ __align__(16) _Float16 Bs[2][2][8192];
    const int z = blockIdx.z;
    gemm_core<1152, 18>(Fp + (size_t)z * 4718592, Wn + (size_t)z * 4718592,
                        S0 + (size_t)z * 16777216, &As[0][0][0], &Bs[0][0][0]);
}

// ---------------------------------------------------------------------------
__global__ __launch_bounds__(256, 1) void gemm2_kernel(const _Float16* __restrict__ Vt,
                                                       const _Float16* __restrict__ att0,
                                                       const _Float16* __restrict__ att1,
                                                       _Float16* __restrict__ OTh) {
    __shared__ __align__(16) _Float16 As[2][2][8192];
    __shared__ __align__(16) _Float16 Bs[2][2][8192];
    const int z = blockIdx.z;
    gemm_core<4096, 64>(Vt + (size_t)z * 8388608, z ? att1 : att0,
                        OTh + (size_t)z * 8388608, &As[0][0][0], &Bs[0][0][0]);
}

// ---------------------------------------------------------------------------
// Fused double 3-tap "fuse" + mask + softmax — vectorized (R7, verified).
__global__ __launch_bounds__(256) void fuse_softmax_kernel(const _Float16* __restrict__ S0,
                                                           const float* __restrict__ mm,
                                                           _Float16* __restrict__ att0,
                                                           _Float16* __restrict__ att1) {
    __shared__ float red[4];
    const int tid = threadIdx.x;
    const int lane = tid & 63;
    const int wave = tid >> 6;
    int g = blockIdx.x;
    int p_global = ((g & 7) << 10) | (g >> 3);
    const int bb = p_global >> 12;
    const int p = p_global & 4095;
    const _Float16* S = S0 + (size_t)bb * 16777216;
    _Float16* att = bb ? att1 : att0;
    const int pbase = ((p & 63) << 6) | (p >> 6);  // T(p)

    const int i  = tid >> 2;
    const int j0 = (tid & 3) << 4;
    const int l0 = tid * 16;

    float acc[16];
    #pragma unroll
    for (int e = 0; e < 16; ++e) acc[e] = 0.f;

    #pragma unroll
    for (int t2 = -1; t2 <= 1; ++t2) {
        int b2 = pbase + t2;
        if ((unsigned)b2 >= 4096u) continue;
        int pp = ((b2 & 63) << 6) | (b2 >> 6);
        const int it2 = i + t2;
        #pragma unroll
        for (int t1 = -1; t1 <= 1; ++t1) {
            int rr = pp + t1;
            if ((unsigned)rr >= 4096u) continue;
            const _Float16* row = S + (size_t)rr * 4096;
            if ((unsigned)it2 < 64u) {
                const int ws = it2 * 64 + j0 - 1;
                float w[18];
                f16x8 v0 = *(const f16x8*)&row[ws + 1];
                f16x8 v1 = *(const f16x8*)&row[ws + 9];
                w[0]  = (ws >= 0) ? (float)row[ws] : 0.f;
                #pragma unroll
                for (int x = 0; x < 8; ++x) {
                    w[1 + x] = (float)v0[x];
                    w[9 + x] = (float)v1[x];
                }
                w[17] = (ws + 17 < 4096) ? (float)row[ws + 17] : 0.f;
                #pragma unroll
                for (int e = 0; e < 16; ++e) acc[e] += w[e + 1 + t1];
            } else if (it2 == 64) {
                #pragma unroll
                for (int e = 0; e < 16; ++e)
                    if (j0 + e <= 62) acc[e] += (float)row[j0 + e + 1 + t1];
            } else {  // it2 == -1
                #pragma unroll
                for (int e = 0; e < 16; ++e)
                    if (j0 + e >= 1) acc[e] += (float)row[4031 + j0 + e + t1];
            }
        }
    }

    float mv[16];
    float lmax = -1e30f;
    #pragma unroll
    for (int e = 0; e < 16; ++e) {
        mv[e] = mm[l0 + e];
        float lg = acc[e] * mv[e] * 10.0f;
        acc[e] = lg;
        lmax = fmaxf(lmax, lg);
    }
    #pragma unroll
    for (int off = 32; off > 0; off >>= 1) lmax = fmaxf(lmax, __shfl_xor(lmax, off));
    if (lane == 0) red[wave] = lmax;
    __syncthreads();
    lmax = fmaxf(fmaxf(red[0], red[1]), fmaxf(red[2], red[3]));
    __syncthreads();

    float lsum = 0.f;
    #pragma unroll
    for (int e = 0; e < 16; ++e) {
        float ex = __expf(acc[e] - lmax);
        acc[e] = ex;
        lsum += ex;
    }
    #pragma unroll
    for (int off = 32; off > 0; off >>= 1) lsum += __shfl_xor(lsum, off);
    if (lane == 0) red[wave] = lsum;
    __syncthreads();
    float inv = 1.0f / (red[0] + red[1] + red[2] + red[3]);

    _Float16 outv[16];
    #pragma unroll
    for (int e = 0; e < 16; ++e) outv[e] = (_Float16)(acc[e] * inv * mv[e]);
    _Float16* dst = att + (size_t)p * 4096 + l0;
    *(f16x8*)&dst[0] = *(const f16x8*)&outv[0];
    *(f16x8*)&dst[8] = *(const f16x8*)&outv[8];
}

// ---------------------------------------------------------------------------
__global__ __launch_bounds__(256) void assemble_kernel(const _Float16* __restrict__ OTh,
                                                       float* __restrict__ out) {
    int idx = blockIdx.x * 256 + threadIdx.x;
    int bb = idx >> 21;
    int w = idx & 2097151;
    const _Float16* OTb = OTh + (size_t)bb * 8388608;
    int x = w & 127, y = (w >> 7) & 127, c = w >> 14;
    int r0 = (y + 1) & 1, s0 = (x + 1) & 1;
    float acc = 0.f;
    #pragma unroll
    for (int a = 0; a < 2; ++a) {
        int rh = r0 + 2 * a;
        int ph = (y + 1 - rh) >> 1;
        if ((unsigned)ph < 64u) {
            #pragma unroll
            for (int bq = 0; bq < 2; ++bq) {
                int rw = s0 + 2 * bq;
                int pw = (x + 1 - rw) >> 1;
                if ((unsigned)pw < 64u)
                    acc += (float)OTb[(size_t)(c * 16 + rh * 4 + rw) * 4096 + ph * 64 + pw];
            }
        }
    }
    out[idx] = 0.25f * acc;
}

// ---------------------------------------------------------------------------
extern "C" void kernel_launch(void* const* d_in, const int* in_sizes, int n_in,
                              void* d_out, int out_size, void* d_ws, size_t ws_size,
                              hipStream_t stream) {
    const float* f = (const float*)d_in[0];
    const float* b = (const float*)d_in[1];
    const float* mask = (const float*)d_in[2];
    float* out = (float*)d_out;
    char* ws = (char*)d_ws;

    // workspace — total 138,428,416 bytes (proven size)
    float* mm = (float*)ws;
    _Float16* Fp = (_Float16*)(ws + 16384);
    _Float16* Wn = (_Float16*)(ws + 16384 + 18874368);
    _Float16* att0 = (_Float16*)(ws + 16384);                 // overlays Fp/Wn (dead)
    _Float16* S0 = (_Float16*)(ws + 37765120);
    _Float16* Vt = (_Float16*)(ws + 37765120);                // overlays S0 b0 (dead)
    _Float16* OTh = (_Float16*)(ws + 37765120 + 33554432);    // overlays S0 b1 (dead)
    float* fds = (float*)(ws + 104873984);
    float* bds = (float*)(ws + 104873984 + 4194304);
    _Float16* att1 = (_Float16*)(ws + 104873984);             // overlays fds/bds (dead)

    downsample_kernel<<<dim3(4096, 2), 256, 0, stream>>>(f, b, fds, bds);
    build_mm_kernel<<<16, 256, 0, stream>>>(mask, mm);
    build_fpatch_kernel<<<8192, 256, 0, stream>>>(fds, Fp);
    build_wn_kernel<<<8192, 256, 0, stream>>>(bds, Wn);

    gemm1_kernel<<<dim3(16, 16, 2), 256, 0, stream>>>(Fp, Wn, S0);
    fuse_softmax_kernel<<<8192, 256, 0, stream>>>(S0, mm, att0, att1);

    build_vt_kernel<<<4096, 256, 0, stream>>>(b, Vt);
    gemm2_kernel<<<dim3(16, 8, 2), 256, 0, stream>>>(Vt, att0, att1, OTh);
    assemble_kernel<<<16384, 256, 0, stream>>>(OTh, out);
}

// Round 9
// 427.655 us; speedup vs baseline: 1.1007x; 1.1007x over previous
//
#include <hip/hip_runtime.h>
#include <cstdint>

typedef _Float16 f16x8 __attribute__((ext_vector_type(8)));
typedef float f32x4 __attribute__((ext_vector_type(4)));
typedef float f32x4v __attribute__((ext_vector_type(4)));

typedef __attribute__((address_space(1))) void gvoid;
typedef __attribute__((address_space(3))) void lvoid;

__device__ __forceinline__ void gload16(const void* g, void* l) {
    __builtin_amdgcn_global_load_lds((gvoid*)g, (lvoid*)l, 16, 0, 0);
}

__device__ __forceinline__ void bar() {
    asm volatile("" ::: "memory");
    __builtin_amdgcn_s_barrier();
    asm volatile("" ::: "memory");
}
#define WAITV(N) asm volatile("s_waitcnt vmcnt(" #N ")" ::: "memory")

// ---------------------------------------------------------------------------
// Downsample f,b (::2,::2) — vectorized: 16 consecutive outputs/thread,
// stride-2 reads via aligned float4 (.x/.z), float4 stores. Values identical.
__global__ __launch_bounds__(256) void downsample_kernel(const float* __restrict__ f,
                                                         const float* __restrict__ b,
                                                         float* __restrict__ fds,
                                                         float* __restrict__ bds) {
    int gid = blockIdx.x * 256 + threadIdx.x;          // 65536 threads
    const float* src = blockIdx.y ? b : f;
    float* dst = blockIdx.y ? bds : fds;
    int idx0 = gid * 16;
    int bb = idx0 >> 19;
    int r = idx0 & 524287;
    int c = r >> 12, a = (r >> 6) & 63, v0 = r & 63;   // v0 in {0,16,32,48}
    const float* sp = src + (size_t)bb * 2097152 + (size_t)c * 16384 + (2 * a) * 128 + 2 * v0;
    float o[16];
    #pragma unroll
    for (int u = 0; u < 8; ++u) {
        f32x4 q = *(const f32x4*)(sp + 4 * u);          // 16B-aligned (v0 mult of 16)
        o[2 * u] = q[0];
        o[2 * u + 1] = q[2];
    }
    #pragma unroll
    for (int k = 0; k < 4; ++k)
        *(f32x4*)&dst[idx0 + 4 * k] = *(const f32x4*)&o[4 * k];
}

// ---------------------------------------------------------------------------
__global__ __launch_bounds__(256) void build_mm_kernel(const float* __restrict__ mask,
                                                       float* __restrict__ mm) {
    int l = blockIdx.x * 256 + threadIdx.x;
    if (l >= 4096) return;
    int i = l >> 6, j = l & 63;
    float s = 0.f;
    #pragma unroll
    for (int dy = 0; dy < 3; ++dy)
        #pragma unroll
        for (int dx = 0; dx < 3; ++dx) {
            int a = i + dy - 1, b = j + dx - 1;
            if ((unsigned)a < 64u && (unsigned)b < 64u)
                s += mask[(2 * a) * 128 + 2 * b];
        }
    mm[l] = (s == 0.0f) ? 1.0f : 0.0f;
}

// ---------------------------------------------------------------------------
__global__ __launch_bounds__(256) void build_fpatch_kernel(const float* __restrict__ fds,
                                                           _Float16* __restrict__ Fp) {
    int bb = blockIdx.x >> 12;
    int p = blockIdx.x & 4095;
    const float* fb = fds + (size_t)bb * 524288;
    _Float16* Fpb = Fp + (size_t)bb * 4718592;
    int u = p >> 6, v = p & 63;
    for (int k = threadIdx.x; k < 1152; k += 256) {
        int c = k / 9;
        int s = k - 9 * c;
        int dy = s / 3, dx = s - 3 * dy;
        int a = u + dy - 1, bcol = v + dx - 1;
        float val = 0.f;
        if ((unsigned)a < 64u && (unsigned)bcol < 64u)
            val = fb[c * 4096 + a * 64 + bcol];
        Fpb[(size_t)p * 1152 + k] = (_Float16)val;
    }
}

// ---------------------------------------------------------------------------
__global__ __launch_bounds__(256) void build_wn_kernel(const float* __restrict__ bds,
                                                       _Float16* __restrict__ Wn) {
    __shared__ float wsh[1152];
    __shared__ float red[4];
    int bb = blockIdx.x >> 12;
    int l = blockIdx.x & 4095;
    const float* bp = bds + (size_t)bb * 524288;
    _Float16* Wnb = Wn + (size_t)bb * 4718592;
    int i = l >> 6, j = l & 63;
    float sq = 0.f;
    for (int k = threadIdx.x; k < 1152; k += 256) {
        int c = k / 9;
        int s = k - 9 * c;
        int dy = s / 3, dx = s - 3 * dy;
        int a = i + dy - 1, bcol = j + dx - 1;
        float val = 0.f;
        if ((unsigned)a < 64u && (unsigned)bcol < 64u)
            val = bp[c * 4096 + a * 64 + bcol];
        wsh[k] = val;
        sq += val * val;
    }
    #pragma unroll
    for (int off = 32; off > 0; off >>= 1) sq += __shfl_xor(sq, off);
    if ((threadIdx.x & 63) == 0) red[threadIdx.x >> 6] = sq;
    __syncthreads();
    float total = red[0] + red[1] + red[2] + red[3] + 0.1152f;
    float rinv = 1.0f / sqrtf(total);
    for (int k = threadIdx.x; k < 1152; k += 256)
        Wnb[(size_t)l * 1152 + k] = (_Float16)(wsh[k] * rinv);
}

// ---------------------------------------------------------------------------
// build_vt — vectorized: 16 consecutive l/thread (row uniform), f16x8 stores.
// Per-element values identical to the scalar original.
__global__ __launch_bounds__(256) void build_vt_kernel(const float* __restrict__ b,
                                                       _Float16* __restrict__ Vt) {
    int bb = blockIdx.x >> 11;
    int n = blockIdx.x & 2047;
    const float* bp = b + (size_t)bb * 2097152;
    _Float16* Vtb = Vt + (size_t)bb * 8388608;
    int c = n >> 4, r = n & 15, rh = r >> 2, rw = r & 3;
    const float* bc = bp + (size_t)c * 16384;
    const int tid = threadIdx.x;
    const int l0 = tid * 16;
    const int lh = l0 >> 6, lw0 = l0 & 63;
    const int row = 2 * lh + rh - 1;
    _Float16 o[16];
    if ((unsigned)row < 128u) {
        const float* rp = bc + row * 128;
        const int col0 = 2 * lw0 + rw - 1;
        #pragma unroll
        for (int e = 0; e < 16; ++e) {
            int col = col0 + 2 * e;
            o[e] = ((unsigned)col < 128u) ? (_Float16)rp[col] : (_Float16)0.f;
        }
    } else {
        #pragma unroll
        for (int e = 0; e < 16; ++e) o[e] = (_Float16)0.f;
    }
    _Float16* dst = Vtb + (size_t)n * 4096 + l0;
    *(f16x8*)&dst[0] = *(const f16x8*)&o[0];
    *(f16x8*)&dst[8] = *(const f16x8*)&o[8];
}

// ---------------------------------------------------------------------------
// 256x256/BK=64 8-phase GEMM core (R7 configuration: 8 waves, 128x64 wave
// tiles — the measured optimum; R8's 128x128/4-wave spilled at 252 VGPR).
// Phase p = { LD(frags p); STAGE; [WAITV(4) @ p4,p8]; bar; MFMA(p); bar }.
// Region/wait schedule (verified R1):
//   issue(i,p1/p2): buf1.Kh1 <- tile 2i+1   (read at i,p7/p8)
//   issue(i,p3/p4): buf0.Kh0 <- tile 2i+2   (read at i+1,p1/p2)
//   issue(i,p5/p6): buf0.Kh1 <- tile 2i+2   (read at i+1,p3/p4)
//   issue(i,p7/p8): buf1.Kh0 <- tile 2i+3   (read at i+1,p5/p6)
// Accumulation order per acc element unchanged -> numerics identical.
template <int KSTR, int NTILES>
__device__ __forceinline__ void gemm_core(const _Float16* __restrict__ A,
                                          const _Float16* __restrict__ Bt,
                                          _Float16* __restrict__ C,
                                          _Float16* __restrict__ AsB,
                                          _Float16* __restrict__ BsB) {
    const int tid = threadIdx.x;
    const int lane = tid & 63;
    const int wave = tid >> 6;
    const int quad = lane >> 4;
    const int l16 = lane & 15;
    const int wm = wave >> 2;
    const int wn = wave & 3;
    const int bm = blockIdx.y * 256;
    const int bn = blockIdx.x * 256;

    f32x4 acc[8][4] = {};

    const int s0 = tid, s1 = 512 + tid;
    const int sr0 = s0 >> 2, sr1 = s1 >> 2;
    const int r0 = sr0 ^ ((sr0 >> 2) & 1);
    const int r1 = sr1 ^ ((sr1 >> 2) & 1);
    const int q0 = (s0 & 3) ^ (r0 & 3);
    const int q1 = (s1 & 3) ^ (r1 & 3);
    const int offA0 = (bm + r0) * KSTR + q0 * 8;
    const int offA1 = (bm + r1) * KSTR + q1 * 8;
    const int offB0 = (bn + r0) * KSTR + q0 * 8;
    const int offB1 = (bn + r1) * KSTR + q1 * 8;

#define STAGE_A(buf, kt, kh) do {                                                          \
        gload16(A + offA0 + (kt) * 64 + (kh) * 32, AsB + ((buf) * 2 + (kh)) * 8192 + tid * 8); \
        gload16(A + offA1 + (kt) * 64 + (kh) * 32, AsB + ((buf) * 2 + (kh)) * 8192 + 4096 + tid * 8); \
    } while (0)
#define STAGE_B(buf, kt, kh) do {                                                          \
        gload16(Bt + offB0 + (kt) * 64 + (kh) * 32, BsB + ((buf) * 2 + (kh)) * 8192 + tid * 8); \
        gload16(Bt + offB1 + (kt) * 64 + (kh) * 32, BsB + ((buf) * 2 + (kh)) * 8192 + 4096 + tid * 8); \
    } while (0)

    const int c2 = (l16 >> 2) & 1;
    const int rdoff = ((l16 ^ c2) * 32) + ((quad ^ (l16 & 3)) * 8);

    f16x8 afr[4], bfr[4];
    auto LDA = [&](int buf, int kh, int mh) {
        #pragma unroll
        for (int mi = 0; mi < 4; ++mi)
            afr[mi] = *(const f16x8*)&AsB[((buf) * 2 + (kh)) * 8192 +
                                          (wm * 128 + ((mh) * 4 + mi) * 16) * 32 + rdoff];
    };
    auto LDB = [&](int buf, int kh) {
        #pragma unroll
        for (int ni = 0; ni < 4; ++ni)
            bfr[ni] = *(const f16x8*)&BsB[((buf) * 2 + (kh)) * 8192 +
                                          (wn * 64 + ni * 16) * 32 + rdoff];
    };
    auto MM = [&](int mh) {
        __builtin_amdgcn_s_setprio(1);
        #pragma unroll
        for (int mi = 0; mi < 4; ++mi)
            #pragma unroll
            for (int ni = 0; ni < 4; ++ni)
                acc[mh * 4 + mi][ni] = __builtin_amdgcn_mfma_f32_16x16x32_f16(
                    afr[mi], bfr[ni], acc[mh * 4 + mi][ni], 0, 0, 0);
        __builtin_amdgcn_s_setprio(0);
    };

    // prologue: 6 half-tile units; keep last 2 in flight
    STAGE_A(0, 0, 0); STAGE_B(0, 0, 0);
    STAGE_A(0, 0, 1); STAGE_B(0, 0, 1);
    STAGE_A(1, 1, 0); STAGE_B(1, 1, 0);
    WAITV(4);
    bar();

    #pragma unroll 1
    for (int i = 0; i < NTILES / 2 - 1; ++i) {
        const int t0 = 2 * i;
        LDA(0, 0, 0); LDB(0, 0); STAGE_A(1, t0 + 1, 1);
        bar(); MM(0); bar();
        LDA(0, 0, 1); STAGE_B(1, t0 + 1, 1);
        bar(); MM(1); bar();
        LDA(0, 1, 0); LDB(0, 1); STAGE_A(0, t0 + 2, 0);
        bar(); MM(0); bar();
        LDA(0, 1, 1); STAGE_B(0, t0 + 2, 0); WAITV(4);
        bar(); MM(1); bar();
        LDA(1, 0, 0); LDB(1, 0); STAGE_A(0, t0 + 2, 1);
        bar(); MM(0); bar();
        LDA(1, 0, 1); STAGE_B(0, t0 + 2, 1);
        bar(); MM(1); bar();
        LDA(1, 1, 0); LDB(1, 1); STAGE_A(1, t0 + 3, 0);
        bar(); MM(0); bar();
        LDA(1, 1, 1); STAGE_B(1, t0 + 3, 0); WAITV(4);
        bar(); MM(1); bar();
    }

    // epilogue: tiles NTILES-2 (buf0), NTILES-1 (buf1); stage buf1.kh1 only
    LDA(0, 0, 0); LDB(0, 0); STAGE_A(1, NTILES - 1, 1);
    bar(); MM(0); bar();
    LDA(0, 0, 1); STAGE_B(1, NTILES - 1, 1);
    bar(); MM(1); bar();
    LDA(0, 1, 0); LDB(0, 1);
    bar(); MM(0); bar();
    LDA(0, 1, 1);
    bar(); MM(1); WAITV(0); bar();
    LDA(1, 0, 0); LDB(1, 0); bar(); MM(0); bar();
    LDA(1, 0, 1);            bar(); MM(1); bar();
    LDA(1, 1, 0); LDB(1, 1); bar(); MM(0); bar();
    LDA(1, 1, 1);            bar(); MM(1);

#undef STAGE_A
#undef STAGE_B

    #pragma unroll
    for (int mi = 0; mi < 8; ++mi)
        #pragma unroll
        for (int ni = 0; ni < 4; ++ni)
            #pragma unroll
            for (int r = 0; r < 4; ++r) {
                int row = bm + wm * 128 + mi * 16 + quad * 4 + r;
                int col = bn + wn * 64 + ni * 16 + l16;
                C[(size_t)row * 4096 + col] = (_Float16)acc[mi][ni][r];
            }
}

// ---------------------------------------------------------------------------
__global__ __launch_bounds__(512, 2) void gemm1_kernel(const _Float16* __restrict__ Fp,
                                                       const _Float16* __restrict__ Wn,
                                                       _Float16* __restrict__ S0) {
    __shared__ __align__(16) _Float16 As[2][2][8192];
    __shared__ __align__(16) _Float16 Bs[2][2][8192];
    const int z = blockIdx.z;
    gemm_core<1152, 18>(Fp + (size_t)z * 4718592, Wn + (size_t)z * 4718592,
                        S0 + (size_t)z * 16777216, &As[0][0][0], &Bs[0][0][0]);
}

// ---------------------------------------------------------------------------
__global__ __launch_bounds__(512, 2) void gemm2_kernel(const _Float16* __restrict__ Vt,
                                                       const _Float16* __restrict__ att0,
                                                       const _Float16* __restrict__ att1,
                                                       _Float16* __restrict__ OTh) {
    __shared__ __align__(16) _Float16 As[2][2][8192];
    __shared__ __align__(16) _Float16 Bs[2][2][8192];
    const int z = blockIdx.z;
    gemm_core<4096, 64>(Vt + (size_t)z * 8388608, z ? att1 : att0,
                        OTh + (size_t)z * 8388608, &As[0][0][0], &Bs[0][0][0]);
}

// ---------------------------------------------------------------------------
// Fused double 3-tap "fuse" + mask + softmax — vectorized (R7, verified).
__global__ __launch_bounds__(256) void fuse_softmax_kernel(const _Float16* __restrict__ S0,
                                                           const float* __restrict__ mm,
                                                           _Float16* __restrict__ att0,
                                                           _Float16* __restrict__ att1) {
    __shared__ float red[4];
    const int tid = threadIdx.x;
    const int lane = tid & 63;
    const int wave = tid >> 6;
    int g = blockIdx.x;
    int p_global = ((g & 7) << 10) | (g >> 3);
    const int bb = p_global >> 12;
    const int p = p_global & 4095;
    const _Float16* S = S0 + (size_t)bb * 16777216;
    _Float16* att = bb ? att1 : att0;
    const int pbase = ((p & 63) << 6) | (p >> 6);  // T(p)

    const int i  = tid >> 2;
    const int j0 = (tid & 3) << 4;
    const int l0 = tid * 16;

    float acc[16];
    #pragma unroll
    for (int e = 0; e < 16; ++e) acc[e] = 0.f;

    #pragma unroll
    for (int t2 = -1; t2 <= 1; ++t2) {
        int b2 = pbase + t2;
        if ((unsigned)b2 >= 4096u) continue;
        int pp = ((b2 & 63) << 6) | (b2 >> 6);
        const int it2 = i + t2;
        #pragma unroll
        for (int t1 = -1; t1 <= 1; ++t1) {
            int rr = pp + t1;
            if ((unsigned)rr >= 4096u) continue;
            const _Float16* row = S + (size_t)rr * 4096;
            if ((unsigned)it2 < 64u) {
                const int ws = it2 * 64 + j0 - 1;
                float w[18];
                f16x8 v0 = *(const f16x8*)&row[ws + 1];
                f16x8 v1 = *(const f16x8*)&row[ws + 9];
                w[0]  = (ws >= 0) ? (float)row[ws] : 0.f;
                #pragma unroll
                for (int x = 0; x < 8; ++x) {
                    w[1 + x] = (float)v0[x];
                    w[9 + x] = (float)v1[x];
                }
                w[17] = (ws + 17 < 4096) ? (float)row[ws + 17] : 0.f;
                #pragma unroll
                for (int e = 0; e < 16; ++e) acc[e] += w[e + 1 + t1];
            } else if (it2 == 64) {
                #pragma unroll
                for (int e = 0; e < 16; ++e)
                    if (j0 + e <= 62) acc[e] += (float)row[j0 + e + 1 + t1];
            } else {  // it2 == -1
                #pragma unroll
                for (int e = 0; e < 16; ++e)
                    if (j0 + e >= 1) acc[e] += (float)row[4031 + j0 + e + t1];
            }
        }
    }

    float mv[16];
    float lmax = -1e30f;
    #pragma unroll
    for (int e = 0; e < 16; ++e) {
        mv[e] = mm[l0 + e];
        float lg = acc[e] * mv[e] * 10.0f;
        acc[e] = lg;
        lmax = fmaxf(lmax, lg);
    }
    #pragma unroll
    for (int off = 32; off > 0; off >>= 1) lmax = fmaxf(lmax, __shfl_xor(lmax, off));
    if (lane == 0) red[wave] = lmax;
    __syncthreads();
    lmax = fmaxf(fmaxf(red[0], red[1]), fmaxf(red[2], red[3]));
    __syncthreads();

    float lsum = 0.f;
    #pragma unroll
    for (int e = 0; e < 16; ++e) {
        float ex = __expf(acc[e] - lmax);
        acc[e] = ex;
        lsum += ex;
    }
    #pragma unroll
    for (int off = 32; off > 0; off >>= 1) lsum += __shfl_xor(lsum, off);
    if (lane == 0) red[wave] = lsum;
    __syncthreads();
    float inv = 1.0f / (red[0] + red[1] + red[2] + red[3]);

    _Float16 outv[16];
    #pragma unroll
    for (int e = 0; e < 16; ++e) outv[e] = (_Float16)(acc[e] * inv * mv[e]);
    _Float16* dst = att + (size_t)p * 4096 + l0;
    *(f16x8*)&dst[0] = *(const f16x8*)&outv[0];
    *(f16x8*)&dst[8] = *(const f16x8*)&outv[8];
}

// ---------------------------------------------------------------------------
__global__ __launch_bounds__(256) void assemble_kernel(const _Float16* __restrict__ OTh,
                                                       float* __restrict__ out) {
    int idx = blockIdx.x * 256 + threadIdx.x;
    int bb = idx >> 21;
    int w = idx & 2097151;
    const _Float16* OTb = OTh + (size_t)bb * 8388608;
    int x = w & 127, y = (w >> 7) & 127, c = w >> 14;
    int r0 = (y + 1) & 1, s0 = (x + 1) & 1;
    float acc = 0.f;
    #pragma unroll
    for (int a = 0; a < 2; ++a) {
        int rh = r0 + 2 * a;
        int ph = (y + 1 - rh) >> 1;
        if ((unsigned)ph < 64u) {
            #pragma unroll
            for (int bq = 0; bq < 2; ++bq) {
                int rw = s0 + 2 * bq;
                int pw = (x + 1 - rw) >> 1;
                if ((unsigned)pw < 64u)
                    acc += (float)OTb[(size_t)(c * 16 + rh * 4 + rw) * 4096 + ph * 64 + pw];
            }
        }
    }
    out[idx] = 0.25f * acc;
}

// ---------------------------------------------------------------------------
extern "C" void kernel_launch(void* const* d_in, const int* in_sizes, int n_in,
                              void* d_out, int out_size, void* d_ws, size_t ws_size,
                              hipStream_t stream) {
    const float* f = (const float*)d_in[0];
    const float* b = (const float*)d_in[1];
    const float* mask = (const float*)d_in[2];
    float* out = (float*)d_out;
    char* ws = (char*)d_ws;

    // workspace — total 138,428,416 bytes (proven size)
    float* mm = (float*)ws;
    _Float16* Fp = (_Float16*)(ws + 16384);
    _Float16* Wn = (_Float16*)(ws + 16384 + 18874368);
    _Float16* att0 = (_Float16*)(ws + 16384);                 // overlays Fp/Wn (dead)
    _Float16* S0 = (_Float16*)(ws + 37765120);
    _Float16* Vt = (_Float16*)(ws + 37765120);                // overlays S0 b0 (dead)
    _Float16* OTh = (_Float16*)(ws + 37765120 + 33554432);    // overlays S0 b1 (dead)
    float* fds = (float*)(ws + 104873984);
    float* bds = (float*)(ws + 104873984 + 4194304);
    _Float16* att1 = (_Float16*)(ws + 104873984);             // overlays fds/bds (dead)

    downsample_kernel<<<dim3(256, 2), 256, 0, stream>>>(f, b, fds, bds);
    build_mm_kernel<<<16, 256, 0, stream>>>(mask, mm);
    build_fpatch_kernel<<<8192, 256, 0, stream>>>(fds, Fp);
    build_wn_kernel<<<8192, 256, 0, stream>>>(bds, Wn);

    gemm1_kernel<<<dim3(16, 16, 2), 512, 0, stream>>>(Fp, Wn, S0);
    fuse_softmax_kernel<<<8192, 256, 0, stream>>>(S0, mm, att0, att1);

    build_vt_kernel<<<4096, 256, 0, stream>>>(b, Vt);
    gemm2_kernel<<<dim3(16, 8, 2), 512, 0, stream>>>(Vt, att0, att1, OTh);
    assemble_kernel<<<16384, 256, 0, stream>>>(OTh, out);
}